// Round 8
// baseline (5867.726 us; speedup 1.0000x reference)
//
#include <hip/hip_runtime.h>

// Teacher-forced GRU + additive attention decoder, MI355X. FLOAT32 I/O.
// Round 8: R7 poll-on-data protocol, fixed for residency deadlock:
// __launch_bounds__(256,2) caps VGPR (R7 likely >256 -> 1 block/CU -> only
// 256/512 spinner blocks resident -> hang). W_dec VGPR array eliminated:
// dec_proj = per-slice partials (wave0, LDS weights) exchanged via canary
// rows, polled+summed concurrently with h inside sync A.
#define BB    32
#define TDEC  400
#define TENC  800
#define EDIM  256
#define GDIM  256
#define ADIM  128
#define IDIM  80
#define G3    768
#define NSL   16    // slices (blocks) per batch element
#define SLH   16    // GDIM/NSL h-elements per slice
#define SLT   50    // TENC/NSL encoder timesteps per slice
#define EPST  136   // encp LDS row stride (u16), 16B aligned
#define ETST  58    // enc_t LDS row stride (u16)
#define CAN   0x7FC00BADu  // NaN canary: finite math never produces it
#define CSTR  272   // ctx-partial row stride (floats): 256 data + sum@256 + pad

typedef unsigned short u16;
typedef unsigned int u32;

__device__ __forceinline__ float b2f(u16 u) {
  union { u32 i; float f; } x; x.i = ((u32)u) << 16; return x.f;
}
__device__ __forceinline__ u16 f2b(float f) {
  union { float f; u32 u; } x; x.f = f;
  u32 u = x.u; u += 0x7fffu + ((u >> 16) & 1u);
  return (u16)(u >> 16);
}
__device__ __forceinline__ void ld8(const u16* p, float* w) {
  const uint4 q = *reinterpret_cast<const uint4*>(p);
  union { u32 i; float f; } c;
  c.i = q.x << 16;          w[0] = c.f;
  c.i = q.x & 0xffff0000u;  w[1] = c.f;
  c.i = q.y << 16;          w[2] = c.f;
  c.i = q.y & 0xffff0000u;  w[3] = c.f;
  c.i = q.z << 16;          w[4] = c.f;
  c.i = q.z & 0xffff0000u;  w[5] = c.f;
  c.i = q.w << 16;          w[6] = c.f;
  c.i = q.w & 0xffff0000u;  w[7] = c.f;
}
__device__ __forceinline__ void ldf8(const float* p, float* w) {
  const float4 a = *reinterpret_cast<const float4*>(p);
  const float4 b = *reinterpret_cast<const float4*>(p + 4);
  w[0] = a.x; w[1] = a.y; w[2] = a.z; w[3] = a.w;
  w[4] = b.x; w[5] = b.y; w[6] = b.z; w[7] = b.w;
}
__device__ __forceinline__ float fsigmoid(float x) {
  return __builtin_amdgcn_rcpf(1.f + __expf(-x));
}
__device__ __forceinline__ float ftanh(float x) {
  float e = __expf(2.f * x);
  return 1.f - 2.f * __builtin_amdgcn_rcpf(e + 1.f);
}
// Relaxed agent-scope ops: bypass L1/L2 to LLC, no cache invalidation.
__device__ __forceinline__ void ast(float* p, float v) {
  __hip_atomic_store(p, v, __ATOMIC_RELAXED, __HIP_MEMORY_SCOPE_AGENT);
}
__device__ __forceinline__ void asti(int* p, u32 v) {
  __hip_atomic_store(p, (int)v, __ATOMIC_RELAXED, __HIP_MEMORY_SCOPE_AGENT);
}
__device__ __forceinline__ u32 aldi(const int* p) {
  return (u32)__hip_atomic_load(p, __ATOMIC_RELAXED, __HIP_MEMORY_SCOPE_AGENT);
}

// ---------------- K0: canary-init the parity exchange buffers ------------------
__global__ __launch_bounds__(256) void k_init(int* __restrict__ XhP,
                                              int* __restrict__ XdP,
                                              int* __restrict__ XcP) {
  const int i = blockIdx.x * 256 + threadIdx.x;
  if (i < 2 * BB * GDIM) XhP[i] = (int)CAN;
  if (i < 2 * BB * NSL * ADIM) XdP[i] = (int)CAN;
  if (i < 2 * BB * NSL * CSTR) XcP[i] = (int)CAN;
}

// ---------------- K1: gi_x[b][t][g] = x_t . W_ih[:, :80] + b_ih (bf16 out) -----
__global__ __launch_bounds__(256) void k_gix(
    const float* __restrict__ gt, const float* __restrict__ W_ih,
    const float* __restrict__ b_ih, u16* __restrict__ gi_x) {
  __shared__ float sc_x[8][IDIM];
  const int tid = threadIdx.x;
  const int b = blockIdx.x / 50;
  const int t0 = (blockIdx.x % 50) * 8;
  for (int idx = tid; idx < 8 * IDIM; idx += 256) {
    int row = idx / IDIM, col = idx % IDIM;
    sc_x[row][col] = gt[((size_t)b * TDEC + t0 + row) * IDIM + col];
  }
  __syncthreads();
  for (int kk = 0; kk < 3; ++kk) {
    const int g = tid + 256 * kk;
    const float* wrow = W_ih + (size_t)g * 336;
    float acc[8] = {0,0,0,0,0,0,0,0};
    #pragma unroll 2
    for (int k8 = 0; k8 < IDIM / 8; ++k8) {
      float w[8]; ldf8(wrow + (k8 << 3), w);
      #pragma unroll
      for (int tt = 0; tt < 8; ++tt) {
        const float* x = &sc_x[tt][k8 << 3];
        acc[tt] += w[0]*x[0] + w[1]*x[1] + w[2]*x[2] + w[3]*x[3]
                 + w[4]*x[4] + w[5]*x[5] + w[6]*x[6] + w[7]*x[7];
      }
    }
    const float bias = b_ih[g];
    #pragma unroll
    for (int tt = 0; tt < 8; ++tt)
      gi_x[((size_t)b * TDEC + t0 + tt) * G3 + g] = f2b(acc[tt] + bias);
  }
}

// ------- K2: enc_proj (bf16) + bf16 copy of enc_feat ---------------------------
__global__ __launch_bounds__(256) void k_encp(
    const float* __restrict__ enc_feat, const float* __restrict__ W_enc,
    u16* __restrict__ encp, u16* __restrict__ enc_bf) {
  __shared__ float sc_x[16][EDIM];
  const int tid = threadIdx.x;
  const int b = blockIdx.x / 50;
  const int te0 = (blockIdx.x % 50) * 16;
  for (int idx = tid; idx < 16 * EDIM; idx += 256) {
    int row = idx >> 8, col = idx & 255;
    sc_x[row][col] = enc_feat[((size_t)b * TENC + te0 + row) * EDIM + col];
  }
  __syncthreads();
  const int a = tid & 127;
  const int tg = tid >> 7;
  const float* wrow = W_enc + (size_t)a * EDIM;
  float acc[8] = {0,0,0,0,0,0,0,0};
  #pragma unroll 4
  for (int k8 = 0; k8 < EDIM / 8; ++k8) {
    float w[8]; ldf8(wrow + (k8 << 3), w);
    #pragma unroll
    for (int tt = 0; tt < 8; ++tt) {
      const float* x = &sc_x[tg * 8 + tt][k8 << 3];
      acc[tt] += w[0]*x[0] + w[1]*x[1] + w[2]*x[2] + w[3]*x[3]
               + w[4]*x[4] + w[5]*x[5] + w[6]*x[6] + w[7]*x[7];
    }
  }
  #pragma unroll
  for (int tt = 0; tt < 8; ++tt)
    encp[((size_t)b * TENC + te0 + tg * 8 + tt) * ADIM + a] = f2b(acc[tt]);
  for (int idx = tid; idx < 16 * EDIM; idx += 256)
    enc_bf[((size_t)b * TENC + te0) * EDIM + idx] = f2b(sc_x[idx >> 8][idx & 255]);
}

// ---------------- K3: persistent step loop (16 blocks per batch elem) ----------
__global__ __launch_bounds__(256, 2) void k_decode(
    const float* __restrict__ W_ih, const float* __restrict__ W_hh,
    const float* __restrict__ b_hh, const float* __restrict__ W_dec,
    const float* __restrict__ b_attn, const float* __restrict__ v_attn,
    const u16* __restrict__ gi_x, const u16* __restrict__ encp,
    const u16* __restrict__ enc_bf, float* __restrict__ stash,
    float* __restrict__ XhP, float* __restrict__ XdP,
    float* __restrict__ XcP, float* __restrict__ out_attn) {
  __shared__ __align__(16) u16 encp_lds[SLT * EPST];   // 13600 B
  __shared__ __align__(16) u16 enc_t[EDIM * ETST];     // 29696 B  [e][te]
  __shared__ u32 sWdp[128 * 9];                        // 4608 B, W_dec[:,slice]
  __shared__ __align__(16) float sc_h[256];            // h(t)
  __shared__ float sc_ing[4][68];   // ctx quarters, stride 68 (conflict-free)
  __shared__ float sc_inh[4][68];   // h quarters
  __shared__ float sc_dec[ADIM];
  __shared__ float sc_g0[48];   // W_ihc.ctx + gi_x
  __shared__ float sc_g1[48];   // W_hh.h + b_hh (shadow-computed)
  __shared__ float sc_w[56];
  __shared__ float sc_v[ADIM];
  __shared__ float sc_ba[ADIM];
  __shared__ float sc_bhh[48];
  __shared__ float sc_gx[48];
  __shared__ float sc_xs[NSL];

  const int tid = threadIdx.x;
  const int b = blockIdx.x & 31;
  const int j = blockIdx.x >> 5;
  const int lane = tid & 63;

  // ---- one-time: gate weights -> registers (quad-split rows) ----
  u32 wctx[32], whh[32];
  #pragma unroll
  for (int i = 0; i < 32; ++i) { wctx[i] = 0u; whh[i] = 0u; }
  if (tid < 192) {
    const int r = tid >> 2, q = tid & 3;
    const int grow = (r >> 4) * 256 + SLH * j + (r & 15);
    const float2* s1 = reinterpret_cast<const float2*>(
        W_ih + (size_t)grow * 336 + 80 + q * 64);
    const float2* s2 = reinterpret_cast<const float2*>(
        W_hh + (size_t)grow * 256 + q * 64);
    #pragma unroll
    for (int i = 0; i < 32; ++i) {
      const float2 v1 = s1[i], v2 = s2[i];
      wctx[i] = (u32)f2b(v1.x) | ((u32)f2b(v1.y) << 16);
      whh[i]  = (u32)f2b(v2.x) | ((u32)f2b(v2.y) << 16);
    }
  }
  // ---- one-time LDS preloads ----
  for (int idx = tid; idx < 128 * 8; idx += 256) {      // W_dec[:, slice j]
    const int a = idx >> 3, k2 = idx & 7;
    const float2 v = *reinterpret_cast<const float2*>(
        W_dec + (size_t)a * GDIM + SLH * j + 2 * k2);
    sWdp[a * 9 + k2] = (u32)f2b(v.x) | ((u32)f2b(v.y) << 16);
  }
  for (int idx = tid; idx < SLT * ADIM; idx += 256) {
    const int te = idx >> 7, a = idx & 127;
    encp_lds[te * EPST + a] = encp[((size_t)b * TENC + SLT * j + te) * ADIM + a];
  }
  for (int idx = tid; idx < SLT * EDIM; idx += 256) {
    const int te = idx >> 8, e = idx & 255;
    enc_t[e * ETST + te] = enc_bf[((size_t)b * TENC + SLT * j + te) * EDIM + e];
  }
  if (tid < ADIM) { sc_v[tid] = v_attn[tid]; sc_ba[tid] = b_attn[tid]; }
  if (tid < 48) {
    const int gate = tid >> 4, i = tid & 15;
    const int grow = gate * 256 + SLH * j + i;
    const float bh = b_hh[grow];
    sc_bhh[tid] = bh;
    sc_g1[tid] = bh;                                   // gh(h=0) = b_hh
    sc_gx[tid] = b2f(gi_x[((size_t)b * TDEC + 0) * G3 + grow]);
  }
  sc_h[tid] = 0.f;
  sc_ing[tid >> 6][tid & 63] = 0.f;
  sc_inh[tid >> 6][tid & 63] = 0.f;
  __syncthreads();

  for (int t = 0; t < TDEC; ++t) {
    const int p = t & 1;
    float* XhPp = XhP + (p * BB + b) * GDIM;
    float* XdPp = XdP + ((p * BB + b) * NSL + j) * ADIM;  // own row
    float* XcPp = XcP + ((p * BB + b) * NSL) * CSTR;
    // -------- G0: ctx-half gate dots (register weights, strided LDS) ---------
    if (tid < 192) {
      const float* act = &sc_ing[tid & 3][0];
      float acc = 0.f;
      #pragma unroll
      for (int i = 0; i < 32; ++i) {
        union { u32 u; float f; } lo, hi;
        lo.u = wctx[i] << 16; hi.u = wctx[i] & 0xffff0000u;
        acc += lo.f * act[2 * i] + hi.f * act[2 * i + 1];
      }
      acc += __shfl_xor(acc, 1);
      acc += __shfl_xor(acc, 2);
      if ((tid & 3) == 0) sc_g0[tid >> 2] = acc + sc_gx[tid >> 2];
    }
    __syncthreads();  // B1
    // -------- wave0: pointwise h + publish h line + dec partial row ----------
    if (tid < 64) {
      float hval = 0.f;
      if (lane < SLH) {
        const float gr = sc_g0[lane] + sc_g1[lane];
        const float gz = sc_g0[SLH + lane] + sc_g1[SLH + lane];
        const float rr = fsigmoid(gr);
        const float zz = fsigmoid(gz);
        const float nn = ftanh(sc_g0[2 * SLH + lane] + rr * sc_g1[2 * SLH + lane]);
        const float hp = sc_h[SLH * j + lane];
        hval = (1.f - zz) * nn + zz * hp;
        ast(&XhPp[SLH * j + lane], hval);
      }
      float hn16[16];
      #pragma unroll
      for (int k = 0; k < 16; ++k) hn16[k] = __shfl(hval, k);
      #pragma unroll
      for (int r2 = 0; r2 < 2; ++r2) {
        const int a = lane + 64 * r2;
        const u32* wp = &sWdp[a * 9];
        float acc = 0.f;
        #pragma unroll
        for (int k2 = 0; k2 < 8; ++k2) {
          const u32 w2 = wp[k2];
          union { u32 u; float f; } lo, hi;
          lo.u = w2 << 16; hi.u = w2 & 0xffff0000u;
          acc += lo.f * hn16[2 * k2] + hi.f * hn16[2 * k2 + 1];
        }
        ast(&XdPp[a], acc);
      }
    }
    // -------- sync A: poll own h word + 16 dec partials (gather = reduce) ----
    {
      const int* hp_ = (const int*)&XhPp[tid];
      const int* dbase = (const int*)(XdP + ((p * BB + b) * NSL) * ADIM
                                      + (tid & 127));
      u32 hu = CAN;
      u32 gotd = (tid < ADIM) ? 0u : 0xFFFFu;
      float dsum = 0.f;
      for (;;) {
        bool done = true;
        if (hu == CAN) { hu = aldi(hp_); if (hu == CAN) done = false; }
        if (gotd != 0xFFFFu) {
          #pragma unroll
          for (int jj = 0; jj < NSL; ++jj) {
            if (!(gotd & (1u << jj))) {
              const u32 u = aldi(dbase + jj * ADIM);
              if (u != CAN) {
                union { u32 uu; float f; } v; v.uu = u;
                dsum += v.f;
                gotd |= (1u << jj);
              }
            }
          }
          if (gotd != 0xFFFFu) done = false;
        }
        if (done) break;
        __builtin_amdgcn_s_sleep(1);
      }
      union { u32 uu; float f; } hv; hv.uu = hu;
      sc_h[tid] = hv.f;
      sc_inh[tid >> 6][tid & 63] = hv.f;
      if (tid < ADIM) sc_dec[tid] = dsum + sc_ba[tid];
    }
    // reset ctx parity 1-p (safe: h-poll done => all blocks read ctx(t-1))
    asti((int*)&XcP[(((1 - p) * BB + b) * NSL + j) * CSTR + tid], CAN);
    if (tid == 0)
      asti((int*)&XcP[(((1 - p) * BB + b) * NSL + j) * CSTR + 256], CAN);
    __syncthreads();  // B2: sc_dec + h in LDS
    // -------- scores from LDS encp (4-way k-split, 200 threads) --------------
    if (tid < 200) {
      const int te = tid >> 2, q4 = tid & 3;
      const u16* ep = &encp_lds[te * EPST + q4 * 32];
      const float* dp = sc_dec + q4 * 32;
      const float* vp = sc_v + q4 * 32;
      float s = 0.f;
      #pragma unroll
      for (int k8 = 0; k8 < 4; ++k8) {
        float w[8]; ld8(ep + (k8 << 3), w);
        #pragma unroll
        for (int i = 0; i < 8; ++i) {
          const int a = (k8 << 3) + i;
          s += ftanh(w[i] + dp[a]) * vp[a];
        }
      }
      s += __shfl_xor(s, 1);
      s += __shfl_xor(s, 2);
      if (q4 == 0) sc_w[te] = __expf(s);  // |s| <= ||v||_1 ~ 5: max-free safe
    } else if (tid < 248) {  // prefetch gi_x(t+1)
      const int gl = tid - 200;
      const int grow = (gl >> 4) * 256 + SLH * j + (gl & 15);
      const int tn = (t + 1 < TDEC) ? t + 1 : t;
      sc_gx[gl] = b2f(gi_x[((size_t)b * TDEC + tn) * G3 + grow]);
    }
    __syncthreads();  // B3: sc_w ready
    // -------- publish sum + ctx partial (plain stores, own row) --------------
    if (tid < 64) {
      float v = (tid < SLT) ? sc_w[tid] : 0.f;
      #pragma unroll
      for (int off = 1; off < 64; off <<= 1) v += __shfl_xor(v, off);
      if (tid == 0) ast(&XcPp[j * CSTR + 256], v);
    }
    {
      const u32* et = reinterpret_cast<const u32*>(&enc_t[tid * ETST]);
      float pc = 0.f;
      #pragma unroll
      for (int k2 = 0; k2 < 25; ++k2) {
        const u32 w2 = et[k2];
        union { u32 u; float f; } lo, hi;
        lo.u = w2 << 16; hi.u = w2 & 0xffff0000u;
        pc += sc_w[2 * k2] * lo.f + sc_w[2 * k2 + 1] * hi.f;
      }
      ast(&XcPp[j * CSTR + tid], pc);
    }
    // -------- shadow: gh(t) while ctx partials propagate ---------------------
    if (tid < 192) {
      const float* act = &sc_inh[tid & 3][0];
      float acc = 0.f;
      #pragma unroll
      for (int i = 0; i < 32; ++i) {
        union { u32 u; float f; } lo, hi;
        lo.u = whh[i] << 16; hi.u = whh[i] & 0xffff0000u;
        acc += lo.f * act[2 * i] + hi.f * act[2 * i + 1];
      }
      acc += __shfl_xor(acc, 1);
      acc += __shfl_xor(acc, 2);
      if ((tid & 3) == 0) sc_g1[tid >> 2] = acc + sc_bhh[tid >> 2];
    }
    // -------- sync B: poll sums (tid<16) + 16 ctx partials per thread --------
    if (tid < NSL) {
      const int* sp = (const int*)&XcPp[tid * CSTR + 256];
      u32 u = aldi(sp);
      while (u == CAN) { __builtin_amdgcn_s_sleep(1); u = aldi(sp); }
      union { u32 uu; float f; } sv; sv.uu = u;
      sc_xs[tid] = sv.f;
    }
    float c = 0.f;
    {
      u32 got = 0;
      while (got != 0xFFFFu) {
        #pragma unroll
        for (int jj = 0; jj < NSL; ++jj) {
          if (!(got & (1u << jj))) {
            const u32 u = aldi((const int*)&XcPp[jj * CSTR + tid]);
            if (u != CAN) {
              union { u32 uu; float f; } v; v.uu = u;
              c += v.f;
              got |= (1u << jj);
            }
          }
        }
        if (got != 0xFFFFu) __builtin_amdgcn_s_sleep(1);
      }
    }
    __syncthreads();  // B4: sc_xs ready (and sc_g1 shadow done)
    // -------- epilogue -------------------------------------------------------
    {
      float S = 0.f;
      #pragma unroll
      for (int jj = 0; jj < NSL; ++jj) S += sc_xs[jj];
      const float invS = __builtin_amdgcn_rcpf(S);
      const float cv = c * invS;
      sc_ing[tid >> 6][tid & 63] = cv;  // ctx(t) for next-step gates
      if (j == 0) stash[((size_t)b * TDEC + t) * 512 + 256 + tid] = cv;
      if (tid < SLH)
        stash[((size_t)b * TDEC + t) * 512 + SLH * j + tid] = sc_h[SLH * j + tid];
      if (tid < SLT)
        out_attn[((size_t)b * TDEC + t) * TENC + SLT * j + tid] =
            sc_w[tid] * invS;
      // reset own h line + dec row of parity p (ctx-poll done => all read them)
      if (tid < SLH) asti((int*)&XhPp[SLH * j + tid], CAN);
      if (tid < 64) {
        asti((int*)&XdPp[tid], CAN);
        asti((int*)&XdPp[tid + 64], CAN);
      }
    }
    __syncthreads();  // B5
  }
}

// ---------------- K4: pred = log_softmax([h;ctx] . W_out^T + b_out) ------------
__global__ __launch_bounds__(256) void k_pred(
    const float* __restrict__ stash, const float* __restrict__ W_out,
    const float* __restrict__ b_out, float* __restrict__ out_pred) {
  __shared__ float sc_s[4][512];
  __shared__ float sc_lp[2][4][IDIM];
  __shared__ float sc_l[4][IDIM];
  __shared__ float sc_lse[4];
  const int tid = threadIdx.x;
  const int b = blockIdx.x / 100;
  const int t0 = (blockIdx.x % 100) * 4;
  for (int idx = tid; idx < 4 * 512; idx += 256)
    sc_s[idx >> 9][idx & 511] = stash[((size_t)b * TDEC + t0) * 512 + idx];
  __syncthreads();
  const int o = tid & 127, kh = tid >> 7;
  if (o < IDIM) {
    const float* wrow = W_out + (size_t)o * 512 + kh * 256;
    float acc[4] = {0,0,0,0};
    #pragma unroll 4
    for (int k8 = 0; k8 < 32; ++k8) {
      float w[8]; ldf8(wrow + (k8 << 3), w);
      #pragma unroll
      for (int tt = 0; tt < 4; ++tt) {
        const float* x = &sc_s[tt][kh * 256 + (k8 << 3)];
        acc[tt] += w[0]*x[0] + w[1]*x[1] + w[2]*x[2] + w[3]*x[3]
                 + w[4]*x[4] + w[5]*x[5] + w[6]*x[6] + w[7]*x[7];
      }
    }
    #pragma unroll
    for (int tt = 0; tt < 4; ++tt) sc_lp[kh][tt][o] = acc[tt];
  }
  __syncthreads();
  if (tid < IDIM) {
    const float bb = b_out[tid];
    #pragma unroll
    for (int tt = 0; tt < 4; ++tt)
      sc_l[tt][tid] = sc_lp[0][tt][tid] + sc_lp[1][tt][tid] + bb;
  }
  __syncthreads();
  {
    const int w = tid >> 6, lane = tid & 63;
    const float a0 = sc_l[w][lane];
    const float a1 = (lane < IDIM - 64) ? sc_l[w][lane + 64] : -1e30f;
    float m = fmaxf(a0, a1);
    #pragma unroll
    for (int off = 1; off < 64; off <<= 1) m = fmaxf(m, __shfl_xor(m, off));
    float e = __expf(a0 - m) + ((lane < IDIM - 64) ? __expf(a1 - m) : 0.f);
    #pragma unroll
    for (int off = 1; off < 64; off <<= 1) e += __shfl_xor(e, off);
    if (lane == 0) sc_lse[w] = m + __logf(e);
  }
  __syncthreads();
  for (int idx = tid; idx < 4 * IDIM; idx += 256) {
    const int tt = idx / IDIM, oo = idx % IDIM;
    out_pred[((size_t)b * TDEC + t0 + tt) * IDIM + oo] =
        sc_l[tt][oo] - sc_lse[tt];
  }
}

extern "C" void kernel_launch(void* const* d_in, const int* in_sizes, int n_in,
                              void* d_out, int out_size, void* d_ws, size_t ws_size,
                              hipStream_t stream) {
  const float* enc_feat = (const float*)d_in[0];
  const float* gt       = (const float*)d_in[1];
  const float* W_ih     = (const float*)d_in[2];
  const float* W_hh     = (const float*)d_in[3];
  const float* b_ih     = (const float*)d_in[4];
  const float* b_hh     = (const float*)d_in[5];
  const float* W_enc    = (const float*)d_in[6];
  const float* W_dec    = (const float*)d_in[7];
  const float* b_attn   = (const float*)d_in[8];
  const float* v_attn   = (const float*)d_in[9];
  const float* W_out    = (const float*)d_in[10];
  const float* b_out    = (const float*)d_in[11];
  float* out_pred = (float*)d_out;
  float* out_attn = out_pred + (size_t)BB * TDEC * IDIM;

  char* ws = (char*)d_ws;
  size_t off = 0;
  u16* gi_x   = (u16*)(ws + off);   off += (size_t)BB * TDEC * G3 * 2;
  u16* encp   = (u16*)(ws + off);   off += (size_t)BB * TENC * ADIM * 2;
  u16* enc_bf = (u16*)(ws + off);   off += (size_t)BB * TENC * EDIM * 2;
  float* stash= (float*)(ws + off); off += (size_t)BB * TDEC * 512 * 4;
  float* XhP  = (float*)(ws + off); off += (size_t)2 * BB * GDIM * 4;
  float* XdP  = (float*)(ws + off); off += (size_t)2 * BB * NSL * ADIM * 4;
  float* XcP  = (float*)(ws + off); off += (size_t)2 * BB * NSL * CSTR * 4;

  hipLaunchKernelGGL(k_init, dim3((2 * BB * NSL * CSTR + 255) / 256), dim3(256),
                     0, stream, (int*)XhP, (int*)XdP, (int*)XcP);
  hipLaunchKernelGGL(k_gix, dim3(BB * 50), dim3(256), 0, stream,
                     gt, W_ih, b_ih, gi_x);
  hipLaunchKernelGGL(k_encp, dim3(BB * 50), dim3(256), 0, stream,
                     enc_feat, W_enc, encp, enc_bf);
  hipLaunchKernelGGL(k_decode, dim3(BB * NSL), dim3(256), 0, stream,
                     W_ih, W_hh, b_hh, W_dec, b_attn, v_attn,
                     gi_x, encp, enc_bf, stash, XhP, XdP, XcP, out_attn);
  hipLaunchKernelGGL(k_pred, dim3(BB * 100), dim3(256), 0, stream,
                     stash, W_out, b_out, out_pred);
}

// Round 9
// 3390.622 us; speedup vs baseline: 1.7306x; 1.7306x over previous
//
#include <hip/hip_runtime.h>

// Teacher-forced GRU + additive attention decoder, MI355X. FLOAT32 I/O.
// Round 9: revert to R6 protocol (flags + atomicAdd accumulators — measured
// best), plus: 4-way banked accumulators (atomic chain depth 16 -> 4),
// R8's conflict-free strided gate-input quarters, packed W_dec LDS,
// j==0-only h stash, __launch_bounds__(256,2).
#define BB    32
#define TDEC  400
#define TENC  800
#define EDIM  256
#define GDIM  256
#define ADIM  128
#define IDIM  80
#define G3    768
#define NSL   16    // slices (blocks) per batch element
#define SLH   16    // GDIM/NSL h-elements per slice
#define SLT   50    // TENC/NSL encoder timesteps per slice
#define FSTR  16    // flag/sum stride in words (64B line each)
#define EPST  136   // encp LDS row stride (u16), 16B aligned
#define ETST  58    // enc_t LDS row stride (u16): 29 u32/row, odd -> no conflicts

typedef unsigned short u16;
typedef unsigned int u32;

__device__ __forceinline__ float b2f(u16 u) {
  union { u32 i; float f; } x; x.i = ((u32)u) << 16; return x.f;
}
__device__ __forceinline__ u16 f2b(float f) {
  union { float f; u32 u; } x; x.f = f;
  u32 u = x.u; u += 0x7fffu + ((u >> 16) & 1u);
  return (u16)(u >> 16);
}
__device__ __forceinline__ void ld8(const u16* p, float* w) {
  const uint4 q = *reinterpret_cast<const uint4*>(p);
  union { u32 i; float f; } c;
  c.i = q.x << 16;          w[0] = c.f;
  c.i = q.x & 0xffff0000u;  w[1] = c.f;
  c.i = q.y << 16;          w[2] = c.f;
  c.i = q.y & 0xffff0000u;  w[3] = c.f;
  c.i = q.z << 16;          w[4] = c.f;
  c.i = q.z & 0xffff0000u;  w[5] = c.f;
  c.i = q.w << 16;          w[6] = c.f;
  c.i = q.w & 0xffff0000u;  w[7] = c.f;
}
__device__ __forceinline__ void ldf8(const float* p, float* w) {
  const float4 a = *reinterpret_cast<const float4*>(p);
  const float4 b = *reinterpret_cast<const float4*>(p + 4);
  w[0] = a.x; w[1] = a.y; w[2] = a.z; w[3] = a.w;
  w[4] = b.x; w[5] = b.y; w[6] = b.z; w[7] = b.w;
}
__device__ __forceinline__ float fsigmoid(float x) {
  return __builtin_amdgcn_rcpf(1.f + __expf(-x));
}
__device__ __forceinline__ float ftanh(float x) {
  float e = __expf(2.f * x);
  return 1.f - 2.f * __builtin_amdgcn_rcpf(e + 1.f);
}
// Relaxed agent-scope ops: bypass L1/L2 to LLC, no cache invalidation.
__device__ __forceinline__ void ast(float* p, float v) {
  __hip_atomic_store(p, v, __ATOMIC_RELAXED, __HIP_MEMORY_SCOPE_AGENT);
}
__device__ __forceinline__ float ald(const float* p) {
  return __hip_atomic_load(p, __ATOMIC_RELAXED, __HIP_MEMORY_SCOPE_AGENT);
}
__device__ __forceinline__ void aadd(float* p, float v) {
  (void)__hip_atomic_fetch_add(p, v, __ATOMIC_RELAXED, __HIP_MEMORY_SCOPE_AGENT);
}

// ---------------- K1: gi_x[b][t][g] = x_t . W_ih[:, :80] + b_ih (bf16 out) -----
__global__ __launch_bounds__(256) void k_gix(
    const float* __restrict__ gt, const float* __restrict__ W_ih,
    const float* __restrict__ b_ih, u16* __restrict__ gi_x) {
  __shared__ float sc_x[8][IDIM];
  const int tid = threadIdx.x;
  const int b = blockIdx.x / 50;
  const int t0 = (blockIdx.x % 50) * 8;
  for (int idx = tid; idx < 8 * IDIM; idx += 256) {
    int row = idx / IDIM, col = idx % IDIM;
    sc_x[row][col] = gt[((size_t)b * TDEC + t0 + row) * IDIM + col];
  }
  __syncthreads();
  for (int kk = 0; kk < 3; ++kk) {
    const int g = tid + 256 * kk;
    const float* wrow = W_ih + (size_t)g * 336;
    float acc[8] = {0,0,0,0,0,0,0,0};
    #pragma unroll 2
    for (int k8 = 0; k8 < IDIM / 8; ++k8) {
      float w[8]; ldf8(wrow + (k8 << 3), w);
      #pragma unroll
      for (int tt = 0; tt < 8; ++tt) {
        const float* x = &sc_x[tt][k8 << 3];
        acc[tt] += w[0]*x[0] + w[1]*x[1] + w[2]*x[2] + w[3]*x[3]
                 + w[4]*x[4] + w[5]*x[5] + w[6]*x[6] + w[7]*x[7];
      }
    }
    const float bias = b_ih[g];
    #pragma unroll
    for (int tt = 0; tt < 8; ++tt)
      gi_x[((size_t)b * TDEC + t0 + tt) * G3 + g] = f2b(acc[tt] + bias);
  }
}

// ------- K2: enc_proj (bf16) + bf16 copy of enc_feat ---------------------------
__global__ __launch_bounds__(256) void k_encp(
    const float* __restrict__ enc_feat, const float* __restrict__ W_enc,
    u16* __restrict__ encp, u16* __restrict__ enc_bf) {
  __shared__ float sc_x[16][EDIM];
  const int tid = threadIdx.x;
  const int b = blockIdx.x / 50;
  const int te0 = (blockIdx.x % 50) * 16;
  for (int idx = tid; idx < 16 * EDIM; idx += 256) {
    int row = idx >> 8, col = idx & 255;
    sc_x[row][col] = enc_feat[((size_t)b * TENC + te0 + row) * EDIM + col];
  }
  __syncthreads();
  const int a = tid & 127;
  const int tg = tid >> 7;
  const float* wrow = W_enc + (size_t)a * EDIM;
  float acc[8] = {0,0,0,0,0,0,0,0};
  #pragma unroll 4
  for (int k8 = 0; k8 < EDIM / 8; ++k8) {
    float w[8]; ldf8(wrow + (k8 << 3), w);
    #pragma unroll
    for (int tt = 0; tt < 8; ++tt) {
      const float* x = &sc_x[tg * 8 + tt][k8 << 3];
      acc[tt] += w[0]*x[0] + w[1]*x[1] + w[2]*x[2] + w[3]*x[3]
               + w[4]*x[4] + w[5]*x[5] + w[6]*x[6] + w[7]*x[7];
    }
  }
  #pragma unroll
  for (int tt = 0; tt < 8; ++tt)
    encp[((size_t)b * TENC + te0 + tg * 8 + tt) * ADIM + a] = f2b(acc[tt]);
  for (int idx = tid; idx < 16 * EDIM; idx += 256)
    enc_bf[((size_t)b * TENC + te0) * EDIM + idx] = f2b(sc_x[idx >> 8][idx & 255]);
}

// ---------------- K3: persistent step loop (16 blocks per batch elem) ----------
__global__ __launch_bounds__(256, 2) void k_decode(
    const float* __restrict__ W_ih, const float* __restrict__ W_hh,
    const float* __restrict__ b_hh, const float* __restrict__ W_dec,
    const float* __restrict__ b_attn, const float* __restrict__ v_attn,
    const u16* __restrict__ gi_x, const u16* __restrict__ encp,
    const u16* __restrict__ enc_bf, float* __restrict__ stash,
    float* __restrict__ Xh, float* __restrict__ Dacc,
    float* __restrict__ Xctxacc, float* __restrict__ Xsumacc,
    int* __restrict__ flagA, int* __restrict__ flagB,
    float* __restrict__ out_attn) {
  __shared__ __align__(16) u16 encp_lds[SLT * EPST];   // 13600 B
  __shared__ __align__(16) u16 enc_t[EDIM * ETST];     // 29696 B  [e][te]
  __shared__ u32 sWdp[128 * 9];                        // 4608 B, W_dec[:,slice]
  __shared__ __align__(16) float sc_h[256];            // h(t)
  __shared__ float sc_ing[4][68];   // ctx quarters, stride 68 (conflict-free)
  __shared__ float sc_inh[4][68];   // h quarters
  __shared__ float sc_dec[ADIM];
  __shared__ float sc_g0[48];   // W_ihc.ctx + gi_x
  __shared__ float sc_g1[48];   // W_hh.h + b_hh (shadow-computed)
  __shared__ float sc_w[56];
  __shared__ float sc_v[ADIM];
  __shared__ float sc_ba[ADIM];
  __shared__ float sc_bhh[48];
  __shared__ float sc_gx[48];
  __shared__ float sc_xs[4];

  const int tid = threadIdx.x;
  const int b = blockIdx.x & 31;
  const int j = blockIdx.x >> 5;
  const int lane = tid & 63;
  const int bank = j & 3;

  // ---- one-time: gate weights -> registers (quad-split rows) ----
  u32 wctx[32], whh[32];
  #pragma unroll
  for (int i = 0; i < 32; ++i) { wctx[i] = 0u; whh[i] = 0u; }
  if (tid < 192) {
    const int r = tid >> 2, q = tid & 3;
    const int grow = (r >> 4) * 256 + SLH * j + (r & 15);
    const float2* s1 = reinterpret_cast<const float2*>(
        W_ih + (size_t)grow * 336 + 80 + q * 64);
    const float2* s2 = reinterpret_cast<const float2*>(
        W_hh + (size_t)grow * 256 + q * 64);
    #pragma unroll
    for (int i = 0; i < 32; ++i) {
      const float2 v1 = s1[i], v2 = s2[i];
      wctx[i] = (u32)f2b(v1.x) | ((u32)f2b(v1.y) << 16);
      whh[i]  = (u32)f2b(v2.x) | ((u32)f2b(v2.y) << 16);
    }
  }
  // ---- one-time LDS preloads ----
  for (int idx = tid; idx < 128 * 8; idx += 256) {      // W_dec[:, slice j]
    const int a = idx >> 3, k2 = idx & 7;
    const float2 v = *reinterpret_cast<const float2*>(
        W_dec + (size_t)a * GDIM + SLH * j + 2 * k2);
    sWdp[a * 9 + k2] = (u32)f2b(v.x) | ((u32)f2b(v.y) << 16);
  }
  for (int idx = tid; idx < SLT * ADIM; idx += 256) {
    const int te = idx >> 7, a = idx & 127;
    encp_lds[te * EPST + a] = encp[((size_t)b * TENC + SLT * j + te) * ADIM + a];
  }
  for (int idx = tid; idx < SLT * EDIM; idx += 256) {
    const int te = idx >> 8, e = idx & 255;
    enc_t[e * ETST + te] = enc_bf[((size_t)b * TENC + SLT * j + te) * EDIM + e];
  }
  if (tid < ADIM) { sc_v[tid] = v_attn[tid]; sc_ba[tid] = b_attn[tid]; }
  if (tid < 48) {
    const int gate = tid >> 4, i = tid & 15;
    const int grow = gate * 256 + SLH * j + i;
    const float bh = b_hh[grow];
    sc_bhh[tid] = bh;
    sc_g1[tid] = bh;                                   // gh(h=0) = b_hh
    sc_gx[tid] = b2f(gi_x[((size_t)b * TDEC + 0) * G3 + grow]);
  }
  sc_h[tid] = 0.f;
  sc_ing[tid >> 6][tid & 63] = 0.f;
  sc_inh[tid >> 6][tid & 63] = 0.f;
  __syncthreads();

  for (int t = 0; t < TDEC; ++t) {
    const int p = t & 1;
    // -------- G0: ctx-half gate dots (register weights, strided LDS) ---------
    if (tid < 192) {
      const float* act = &sc_ing[tid & 3][0];
      float acc = 0.f;
      #pragma unroll
      for (int i = 0; i < 32; ++i) {
        union { u32 u; float f; } lo, hi;
        lo.u = wctx[i] << 16; hi.u = wctx[i] & 0xffff0000u;
        acc += lo.f * act[2 * i] + hi.f * act[2 * i + 1];
      }
      acc += __shfl_xor(acc, 1);
      acc += __shfl_xor(acc, 2);
      if ((tid & 3) == 0) sc_g0[tid >> 2] = acc + sc_gx[tid >> 2];
    }
    __syncthreads();  // B1: sc_g0 ready (sc_g1 from prev step's shadow)
    // -------- wave0: pointwise h + publish h line + dec partial (banked) -----
    if (tid < 64) {
      float hval = 0.f;
      if (lane < SLH) {
        const float gr = sc_g0[lane] + sc_g1[lane];
        const float gz = sc_g0[SLH + lane] + sc_g1[SLH + lane];
        const float rr = fsigmoid(gr);
        const float zz = fsigmoid(gz);
        const float nn = ftanh(sc_g0[2 * SLH + lane] + rr * sc_g1[2 * SLH + lane]);
        const float hp = sc_h[SLH * j + lane];
        hval = (1.f - zz) * nn + zz * hp;
        ast(&Xh[b * GDIM + SLH * j + lane], hval);
      }
      float hn16[16];
      #pragma unroll
      for (int k = 0; k < 16; ++k) hn16[k] = __shfl(hval, k);
      #pragma unroll
      for (int r2 = 0; r2 < 2; ++r2) {
        const int a = lane + 64 * r2;
        const u32* wp = &sWdp[a * 9];
        float acc = 0.f;
        #pragma unroll
        for (int k2 = 0; k2 < 8; ++k2) {
          const u32 w2 = wp[k2];
          union { u32 u; float f; } lo, hi;
          lo.u = w2 << 16; hi.u = w2 & 0xffff0000u;
          acc += lo.f * hn16[2 * k2] + hi.f * hn16[2 * k2 + 1];
        }
        aadd(&Dacc[((p * BB + b) * 4 + bank) * ADIM + a], acc);
      }
    }
    __syncthreads();  // B2: drains Xh stores + Dacc adds
    if (tid == 0)
      __hip_atomic_store(&flagA[(b * NSL + j) * FSTR], t + 1, __ATOMIC_RELAXED,
                         __HIP_MEMORY_SCOPE_AGENT);
    if (tid < NSL) {
      const int* fp = &flagA[(b * NSL + tid) * FSTR];
      while (__hip_atomic_load(fp, __ATOMIC_RELAXED,
                               __HIP_MEMORY_SCOPE_AGENT) < t + 1)
        __builtin_amdgcn_s_sleep(1);
    }
    __syncthreads();  // B3: sync A done
    {
      const float hv = ald(&Xh[b * GDIM + tid]);        // full h(t)
      sc_h[tid] = hv;
      sc_inh[tid >> 6][tid & 63] = hv;
      if (j == 0) stash[((size_t)b * TDEC + t) * 512 + tid] = hv;
    }
    if (tid < ADIM) {
      float d = sc_ba[tid];
      #pragma unroll
      for (int k = 0; k < 4; ++k)
        d += ald(&Dacc[((p * BB + b) * 4 + k) * ADIM + tid]);
      sc_dec[tid] = d;
    }
    // parity resets for 1-p (consumed at t-1; next adds at t+1)
    if (tid < 64) {  // Xctxacc: 4*256=1024 words; block j resets [64j,64j+64)
      const int w = j * 64 + tid;
      ast(&Xctxacc[(((1 - p) * BB + b) * 4 + (w >> 8)) * EDIM + (w & 255)], 0.f);
    } else if (tid < 96) {  // Dacc: 4*128=512 words; block j resets [32j,32j+32)
      const int w = j * 32 + (tid - 64);
      ast(&Dacc[(((1 - p) * BB + b) * 4 + (w >> 7)) * ADIM + (w & 127)], 0.f);
    } else if (tid == 96 && j < 4) {
      ast(&Xsumacc[(((1 - p) * BB + b) * 4 + j) * FSTR], 0.f);
    }
    __syncthreads();  // B4: sc_dec + h in LDS
    // -------- scores from LDS encp (4-way k-split, 200 threads) --------------
    if (tid < 200) {
      const int te = tid >> 2, q4 = tid & 3;
      const u16* ep = &encp_lds[te * EPST + q4 * 32];
      const float* dp = sc_dec + q4 * 32;
      const float* vp = sc_v + q4 * 32;
      float s = 0.f;
      #pragma unroll
      for (int k8 = 0; k8 < 4; ++k8) {
        float w[8]; ld8(ep + (k8 << 3), w);
        #pragma unroll
        for (int i = 0; i < 8; ++i) {
          const int a = (k8 << 3) + i;
          s += ftanh(w[i] + dp[a]) * vp[a];
        }
      }
      s += __shfl_xor(s, 1);
      s += __shfl_xor(s, 2);
      if (q4 == 0) sc_w[te] = __expf(s);  // |s| <= ||v||_1 ~ 5: max-free safe
    } else if (tid < 248) {  // prefetch gi_x(t+1)
      const int gl = tid - 200;
      const int grow = (gl >> 4) * 256 + SLH * j + (gl & 15);
      const int tn = (t + 1 < TDEC) ? t + 1 : t;
      sc_gx[gl] = b2f(gi_x[((size_t)b * TDEC + tn) * G3 + grow]);
    }
    __syncthreads();  // B5: sc_w ready
    // -------- publish sum + ctx partial (banked atomic accumulate) -----------
    if (tid < 64) {
      float v = (tid < SLT) ? sc_w[tid] : 0.f;
      #pragma unroll
      for (int off = 1; off < 64; off <<= 1) v += __shfl_xor(v, off);
      if (tid == 0) aadd(&Xsumacc[((p * BB + b) * 4 + bank) * FSTR], v);
    }
    {
      const u32* et = reinterpret_cast<const u32*>(&enc_t[tid * ETST]);
      float pc = 0.f;
      #pragma unroll
      for (int k2 = 0; k2 < 25; ++k2) {
        const u32 w2 = et[k2];
        union { u32 u; float f; } lo, hi;
        lo.u = w2 << 16; hi.u = w2 & 0xffff0000u;
        pc += sc_w[2 * k2] * lo.f + sc_w[2 * k2 + 1] * hi.f;
      }
      aadd(&Xctxacc[((p * BB + b) * 4 + bank) * EDIM + tid], pc);
    }
    // -------- shadow: gh(t) while ctx adds propagate -------------------------
    if (tid < 192) {
      const float* act = &sc_inh[tid & 3][0];
      float acc = 0.f;
      #pragma unroll
      for (int i = 0; i < 32; ++i) {
        union { u32 u; float f; } lo, hi;
        lo.u = whh[i] << 16; hi.u = whh[i] & 0xffff0000u;
        acc += lo.f * act[2 * i] + hi.f * act[2 * i + 1];
      }
      acc += __shfl_xor(acc, 1);
      acc += __shfl_xor(acc, 2);
      if ((tid & 3) == 0) sc_g1[tid >> 2] = acc + sc_bhh[tid >> 2];
    }
    __syncthreads();  // B6: drains sum/ctx adds (and sc_g1 shadow done)
    if (tid == 0)
      __hip_atomic_store(&flagB[(b * NSL + j) * FSTR], t + 1, __ATOMIC_RELAXED,
                         __HIP_MEMORY_SCOPE_AGENT);
    if (tid < NSL) {
      const int* fp = &flagB[(b * NSL + tid) * FSTR];
      while (__hip_atomic_load(fp, __ATOMIC_RELAXED,
                               __HIP_MEMORY_SCOPE_AGENT) < t + 1)
        __builtin_amdgcn_s_sleep(1);
      if (tid < 4) sc_xs[tid] = ald(&Xsumacc[((p * BB + b) * 4 + tid) * FSTR]);
    }
    __syncthreads();  // B7: sync B done, sc_xs ready
    // -------- epilogue -------------------------------------------------------
    {
      const float S = sc_xs[0] + sc_xs[1] + sc_xs[2] + sc_xs[3];
      float c = 0.f;
      #pragma unroll
      for (int k = 0; k < 4; ++k)
        c += ald(&Xctxacc[((p * BB + b) * 4 + k) * EDIM + tid]);
      const float invS = __builtin_amdgcn_rcpf(S);
      const float cv = c * invS;
      sc_ing[tid >> 6][tid & 63] = cv;  // ctx(t) for next-step gates
      if (j == 0) stash[((size_t)b * TDEC + t) * 512 + 256 + tid] = cv;
      if (tid < SLT)
        out_attn[((size_t)b * TDEC + t) * TENC + SLT * j + tid] =
            sc_w[tid] * invS;
    }
    __syncthreads();  // B8
  }
}

// ---------------- K4: pred = log_softmax([h;ctx] . W_out^T + b_out) ------------
__global__ __launch_bounds__(256) void k_pred(
    const float* __restrict__ stash, const float* __restrict__ W_out,
    const float* __restrict__ b_out, float* __restrict__ out_pred) {
  __shared__ float sc_s[4][512];
  __shared__ float sc_lp[2][4][IDIM];
  __shared__ float sc_l[4][IDIM];
  __shared__ float sc_lse[4];
  const int tid = threadIdx.x;
  const int b = blockIdx.x / 100;
  const int t0 = (blockIdx.x % 100) * 4;
  for (int idx = tid; idx < 4 * 512; idx += 256)
    sc_s[idx >> 9][idx & 511] = stash[((size_t)b * TDEC + t0) * 512 + idx];
  __syncthreads();
  const int o = tid & 127, kh = tid >> 7;
  if (o < IDIM) {
    const float* wrow = W_out + (size_t)o * 512 + kh * 256;
    float acc[4] = {0,0,0,0};
    #pragma unroll 4
    for (int k8 = 0; k8 < 32; ++k8) {
      float w[8]; ldf8(wrow + (k8 << 3), w);
      #pragma unroll
      for (int tt = 0; tt < 4; ++tt) {
        const float* x = &sc_s[tt][kh * 256 + (k8 << 3)];
        acc[tt] += w[0]*x[0] + w[1]*x[1] + w[2]*x[2] + w[3]*x[3]
                 + w[4]*x[4] + w[5]*x[5] + w[6]*x[6] + w[7]*x[7];
      }
    }
    #pragma unroll
    for (int tt = 0; tt < 4; ++tt) sc_lp[kh][tt][o] = acc[tt];
  }
  __syncthreads();
  if (tid < IDIM) {
    const float bb = b_out[tid];
    #pragma unroll
    for (int tt = 0; tt < 4; ++tt)
      sc_l[tt][tid] = sc_lp[0][tt][tid] + sc_lp[1][tt][tid] + bb;
  }
  __syncthreads();
  {
    const int w = tid >> 6, lane = tid & 63;
    const float a0 = sc_l[w][lane];
    const float a1 = (lane < IDIM - 64) ? sc_l[w][lane + 64] : -1e30f;
    float m = fmaxf(a0, a1);
    #pragma unroll
    for (int off = 1; off < 64; off <<= 1) m = fmaxf(m, __shfl_xor(m, off));
    float e = __expf(a0 - m) + ((lane < IDIM - 64) ? __expf(a1 - m) : 0.f);
    #pragma unroll
    for (int off = 1; off < 64; off <<= 1) e += __shfl_xor(e, off);
    if (lane == 0) sc_lse[w] = m + __logf(e);
  }
  __syncthreads();
  for (int idx = tid; idx < 4 * IDIM; idx += 256) {
    const int tt = idx / IDIM, oo = idx % IDIM;
    out_pred[((size_t)b * TDEC + t0 + tt) * IDIM + oo] =
        sc_l[tt][oo] - sc_lse[tt];
  }
}

extern "C" void kernel_launch(void* const* d_in, const int* in_sizes, int n_in,
                              void* d_out, int out_size, void* d_ws, size_t ws_size,
                              hipStream_t stream) {
  const float* enc_feat = (const float*)d_in[0];
  const float* gt       = (const float*)d_in[1];
  const float* W_ih     = (const float*)d_in[2];
  const float* W_hh     = (const float*)d_in[3];
  const float* b_ih     = (const float*)d_in[4];
  const float* b_hh     = (const float*)d_in[5];
  const float* W_enc    = (const float*)d_in[6];
  const float* W_dec    = (const float*)d_in[7];
  const float* b_attn   = (const float*)d_in[8];
  const float* v_attn   = (const float*)d_in[9];
  const float* W_out    = (const float*)d_in[10];
  const float* b_out    = (const float*)d_in[11];
  float* out_pred = (float*)d_out;
  float* out_attn = out_pred + (size_t)BB * TDEC * IDIM;

  char* ws = (char*)d_ws;
  size_t off = 0;
  u16* gi_x   = (u16*)(ws + off);   off += (size_t)BB * TDEC * G3 * 2;
  u16* encp   = (u16*)(ws + off);   off += (size_t)BB * TENC * ADIM * 2;
  u16* enc_bf = (u16*)(ws + off);   off += (size_t)BB * TENC * EDIM * 2;
  float* stash= (float*)(ws + off); off += (size_t)BB * TDEC * 512 * 4;
  float* Xh   = (float*)(ws + off); off += (size_t)BB * GDIM * 4;
  // ---- zeroed region (one memset): flags + banked accumulators ----
  char* zbase = ws + off;
  int* flagA    = (int*)(ws + off);   off += (size_t)BB * NSL * FSTR * 4;
  int* flagB    = (int*)(ws + off);   off += (size_t)BB * NSL * FSTR * 4;
  float* Dacc   = (float*)(ws + off); off += (size_t)BB * 2 * 4 * ADIM * 4;
  float* Xctxacc= (float*)(ws + off); off += (size_t)BB * 2 * 4 * EDIM * 4;
  float* Xsumacc= (float*)(ws + off); off += (size_t)BB * 2 * 4 * FSTR * 4;
  const size_t zbytes = (size_t)(ws + off - zbase);

  hipMemsetAsync(zbase, 0, zbytes, stream);

  hipLaunchKernelGGL(k_gix, dim3(BB * 50), dim3(256), 0, stream,
                     gt, W_ih, b_ih, gi_x);
  hipLaunchKernelGGL(k_encp, dim3(BB * 50), dim3(256), 0, stream,
                     enc_feat, W_enc, encp, enc_bf);
  hipLaunchKernelGGL(k_decode, dim3(BB * NSL), dim3(256), 0, stream,
                     W_ih, W_hh, b_hh, W_dec, b_attn, v_attn,
                     gi_x, encp, enc_bf, stash, Xh, Dacc, Xctxacc, Xsumacc,
                     flagA, flagB, out_attn);
  hipLaunchKernelGGL(k_pred, dim3(BB * 100), dim3(256), 0, stream,
                     stash, W_out, b_out, out_pred);
}